// Round 2
// baseline (1473.222 us; speedup 1.0000x reference)
//
#include <hip/hip_runtime.h>
#include <hip/hip_bf16.h>
#include <stdint.h>

typedef unsigned short u16;

#define K_OUT 11008
#define N_IN  4096
#define B_SZ  8192
#define NGRP  64

#define BM 256
#define BN 256
#define BK 64

#define NXT (K_OUT / BN)   // 43 tiles along out-K
#define NYT (B_SZ / BM)    // 32 tiles along batch
#define NWG (NXT * NYT)    // 1376 (% 8 == 0 -> bijective XCD chunking)
#define CPX (NWG / 8)      // 172 blocks per XCD chunk

typedef __attribute__((ext_vector_type(8))) __bf16 bf16x8;
typedef __attribute__((ext_vector_type(8))) u16 u16x8;
typedef __attribute__((ext_vector_type(4))) float floatx4;

__device__ __forceinline__ u16 f2bf(float f) {
    union { float f; uint32_t u; } v; v.f = f;
    uint32_t u = v.u;
    return (u16)((u + 0x7fffu + ((u >> 16) & 1u)) >> 16);  // RNE
}

__device__ __forceinline__ void gll16(const u16* g, u16* l) {
    __builtin_amdgcn_global_load_lds(
        (const __attribute__((address_space(1))) unsigned int*)g,
        (__attribute__((address_space(3))) unsigned int*)l,
        16, 0, 0);
}

// xm[b,n] = bf16(x[b,n] * mu1[n]) ; 8 elems/thread, 16B stores
__global__ __launch_bounds__(256) void prep_x_kernel(const float* __restrict__ x,
                                                     const float* __restrict__ mu1,
                                                     u16* __restrict__ xm) {
    int i = (blockIdx.x * blockDim.x + threadIdx.x) * 8;
    float4 xv0 = *(const float4*)(x + i);
    float4 xv1 = *(const float4*)(x + i + 4);
    int n = i & (N_IN - 1);
    float4 mv0 = *(const float4*)(mu1 + n);
    float4 mv1 = *(const float4*)(mu1 + n + 4);
    u16x8 o;
    o[0] = f2bf(xv0.x * mv0.x); o[1] = f2bf(xv0.y * mv0.y);
    o[2] = f2bf(xv0.z * mv0.z); o[3] = f2bf(xv0.w * mv0.w);
    o[4] = f2bf(xv1.x * mv1.x); o[5] = f2bf(xv1.y * mv1.y);
    o[6] = f2bf(xv1.z * mv1.z); o[7] = f2bf(xv1.w * mv1.w);
    *(u16x8*)(xm + i) = o;
}

// Wb[k,n] = bf16((Wq[k,n] - zeros[k,g]) * scales[k,g] * mu2[k]) ; 8 elems/thread
__global__ __launch_bounds__(256) void prep_w_kernel(const int* __restrict__ Wq,
                                                     const float* __restrict__ zeros,
                                                     const float* __restrict__ scales,
                                                     const float* __restrict__ mu2,
                                                     u16* __restrict__ Wb) {
    int i = (blockIdx.x * blockDim.x + threadIdx.x) * 8;
    int k = i >> 12;            // / N_IN
    int n = i & (N_IN - 1);
    int g = n >> 6;             // all 8 elems same group (8 | 64)
    float z = zeros[k * NGRP + g];
    float s = scales[k * NGRP + g] * mu2[k];
    int4 q0 = *(const int4*)(Wq + i);
    int4 q1 = *(const int4*)(Wq + i + 4);
    u16x8 o;
    o[0] = f2bf(((float)q0.x - z) * s); o[1] = f2bf(((float)q0.y - z) * s);
    o[2] = f2bf(((float)q0.z - z) * s); o[3] = f2bf(((float)q0.w - z) * s);
    o[4] = f2bf(((float)q1.x - z) * s); o[5] = f2bf(((float)q1.y - z) * s);
    o[6] = f2bf(((float)q1.z - z) * s); o[7] = f2bf(((float)q1.w - z) * s);
    *(u16x8*)(Wb + i) = o;
}

// ---------------------------------------------------------------------------
// C[M=8192, K_OUT=11008] = A[M,4096] * Bt[K_OUT,4096]^T, bf16 in / fp32 out.
// 256x256 tile, BK=64, 8 waves (2Mx4N), each wave 128x64 via 8x4 x 16x16x32 mfma.
// 8-phase schedule, counted vmcnt (T3+T4), setprio (T5), XOR-swizzled LDS (T2),
// XCD-chunked block swizzle (T1), NONTEMPORAL C stores (keep A/B L3-resident).
//
// vmcnt ledger (calls = global_load_lds instrs/wave; 2 per half, 8 per tile):
//   prologue: A0(4) B0(4) A1(4)            -> vmcnt(4): tile0 done, A1 in flight
//   tile T:   ph0 +B(T+1)h0(2), ph1 +B(T+1)h1(2), ph3 +A(T+2)(4) -> vmcnt(4)
//             => drains A(T+1)+B(T+1); only A(T+2)'s 4 calls stay in flight.
//   overwrite safety: B(T+1)->sB[buf^1] (dead since T-1); A(T+2)->sA[buf],
//             issued ph3, one barrier after last sA[buf] read (ph2).
//   tail: T=62 stages B63 only, vmcnt(0); T=63 pure compute.
// sched_barrier(0) policy (m141: don't over-pin): exactly two per phase —
//   after lgkmcnt(0) (rule #18: stop MFMA hoisting above the wait) and
//   after the MFMA cluster (stop pure MFMAs sinking past setprio/barrier).
// ---------------------------------------------------------------------------

#define GLL_HALF(Sdst, Gbase, R0, KB) do {                                        \
    gll16((Gbase) + (size_t)(R0) * N_IN + (KB), &(Sdst)[((R0) + w8) * BK]);       \
    gll16((Gbase) + (size_t)((R0) + 64) * N_IN + (KB), &(Sdst)[((R0) + 64 + w8) * BK]); \
} while (0)

#define VM4 asm volatile("s_waitcnt vmcnt(4)" ::: "memory")
#define VM0 asm volatile("s_waitcnt vmcnt(0)" ::: "memory")
#define NOWAIT ((void)0)

#define PHASE_MID()                                              \
    __builtin_amdgcn_s_barrier();                                \
    asm volatile("s_waitcnt lgkmcnt(0)" ::: "memory");           \
    __builtin_amdgcn_sched_barrier(0);                           \
    __builtin_amdgcn_s_setprio(1);

#define PHASE_END()                                              \
    __builtin_amdgcn_sched_barrier(0);                           \
    __builtin_amdgcn_s_setprio(0);                               \
    __builtin_amdgcn_s_barrier();

#define TILE(BUF, KB, DO_B, DO_A, WAITSTMT) do {                                  \
    const u16* sAb = sA[BUF];                                                     \
    const u16* sBb = sB[BUF];                                                     \
    bf16x8 aL[4][2], aH[4][2], bL[2][2], bH[2][2];                                \
    /* ---- phase 0: read A-lo(8) + B-lo(4); stage next-B h0; MFMA q0 ---- */     \
    _Pragma("unroll")                                                             \
    for (int mi = 0; mi < 4; ++mi) {                                              \
        const int row = wr128 + mi * 16 + l16;                                    \
        _Pragma("unroll")                                                         \
        for (int ks = 0; ks < 2; ++ks) {                                          \
            const int pc = (ks * 4 + lquad) ^ (row & 7);                          \
            aL[mi][ks] = *(const bf16x8*)&sAb[row * BK + pc * 8];                 \
        }                                                                         \
    }                                                                             \
    _Pragma("unroll")                                                             \
    for (int ni = 0; ni < 2; ++ni) {                                              \
        const int row = wc64 + ni * 16 + l16;                                     \
        _Pragma("unroll")                                                         \
        for (int ks = 0; ks < 2; ++ks) {                                          \
            const int pc = (ks * 4 + lquad) ^ (row & 7);                          \
            bL[ni][ks] = *(const bf16x8*)&sBb[row * BK + pc * 8];                 \
        }                                                                         \
    }                                                                             \
    if (DO_B) GLL_HALF(sB[1 - (BUF)], Bb, 0, (KB) + BK);                          \
    PHASE_MID()                                                                   \
    _Pragma("unroll")                                                             \
    for (int ks = 0; ks < 2; ++ks)                                                \
        _Pragma("unroll")                                                         \
        for (int mi = 0; mi < 4; ++mi)                                            \
            _Pragma("unroll")                                                     \
            for (int ni = 0; ni < 2; ++ni)                                        \
                acc[mi][ni] = __builtin_amdgcn_mfma_f32_16x16x32_bf16(            \
                    aL[mi][ks], bL[ni][ks], acc[mi][ni], 0, 0, 0);                \
    PHASE_END()                                                                   \
    /* ---- phase 1: read B-hi(4); stage next-B h1; MFMA q1 ---- */               \
    _Pragma("unroll")                                                             \
    for (int ni = 0; ni < 2; ++ni) {                                              \
        const int row = wc64 + (ni + 2) * 16 + l16;                               \
        _Pragma("unroll")                                                         \
        for (int ks = 0; ks < 2; ++ks) {                                          \
            const int pc = (ks * 4 + lquad) ^ (row & 7);                          \
            bH[ni][ks] = *(const bf16x8*)&sBb[row * BK + pc * 8];                 \
        }                                                                         \
    }                                                                             \
    if (DO_B) GLL_HALF(sB[1 - (BUF)], Bb, 128, (KB) + BK);                        \
    PHASE_MID()                                                                   \
    _Pragma("unroll")                                                             \
    for (int ks = 0; ks < 2; ++ks)                                                \
        _Pragma("unroll")                                                         \
        for (int mi = 0; mi < 4; ++mi)                                            \
            _Pragma("unroll")                                                     \
            for (int ni = 0; ni < 2; ++ni)                                        \
                acc[mi][ni + 2] = __builtin_amdgcn_mfma_f32_16x16x32_bf16(        \
                    aL[mi][ks], bH[ni][ks], acc[mi][ni + 2], 0, 0, 0);            \
    PHASE_END()                                                                   \
    /* ---- phase 2: read A-hi(8); MFMA q2 ---- */                                \
    _Pragma("unroll")                                                             \
    for (int mi = 0; mi < 4; ++mi) {                                              \
        const int row = wr128 + (mi + 4) * 16 + l16;                              \
        _Pragma("unroll")                                                         \
        for (int ks = 0; ks < 2; ++ks) {                                          \
            const int pc = (ks * 4 + lquad) ^ (row & 7);                          \
            aH[mi][ks] = *(const bf16x8*)&sAb[row * BK + pc * 8];                 \
        }                                                                         \
    }                                                                             \
    PHASE_MID()                                                                   \
    _Pragma("unroll")                                                             \
    for (int ks = 0; ks < 2; ++ks)                                                \
        _Pragma("unroll")                                                         \
        for (int mi = 0; mi < 4; ++mi)                                            \
            _Pragma("unroll")                                                     \
            for (int ni = 0; ni < 2; ++ni)                                        \
                acc[mi + 4][ni] = __builtin_amdgcn_mfma_f32_16x16x32_bf16(        \
                    aH[mi][ks], bL[ni][ks], acc[mi + 4][ni], 0, 0, 0);            \
    PHASE_END()                                                                   \
    /* ---- phase 3: stage next-next A (sA[buf] dead after ph2); MFMA q3 ---- */  \
    if (DO_A) {                                                                   \
        GLL_HALF(sA[BUF], Ab, 0, (KB) + 2 * BK);                                  \
        GLL_HALF(sA[BUF], Ab, 128, (KB) + 2 * BK);                                \
    }                                                                             \
    __builtin_amdgcn_s_barrier();                                                 \
    __builtin_amdgcn_sched_barrier(0);                                            \
    __builtin_amdgcn_s_setprio(1);                                                \
    _Pragma("unroll")                                                             \
    for (int ks = 0; ks < 2; ++ks)                                                \
        _Pragma("unroll")                                                         \
        for (int mi = 0; mi < 4; ++mi)                                            \
            _Pragma("unroll")                                                     \
            for (int ni = 0; ni < 2; ++ni)                                        \
                acc[mi + 4][ni + 2] = __builtin_amdgcn_mfma_f32_16x16x32_bf16(    \
                    aH[mi][ks], bH[ni][ks], acc[mi + 4][ni + 2], 0, 0, 0);        \
    __builtin_amdgcn_sched_barrier(0);                                            \
    __builtin_amdgcn_s_setprio(0);                                                \
    WAITSTMT;                                                                     \
    __builtin_amdgcn_s_barrier();                                                 \
} while (0)

__global__ __launch_bounds__(512, 2) void gemm_bt_kernel(const u16* __restrict__ A,
                                                         const u16* __restrict__ Bt,
                                                         float* __restrict__ C) {
    __shared__ __align__(16) u16 sA[2][BM * BK];   // 2 x 32 KB
    __shared__ __align__(16) u16 sB[2][BN * BK];   // 2 x 32 KB  (128 KiB total)

    const int tid   = threadIdx.x;
    const int w     = tid >> 6;          // wave 0..7
    const int lane  = tid & 63;
    const int lquad = lane >> 4;
    const int l16   = lane & 15;
    const int wr128 = (w >> 2) * 128;    // wave M-offset (2 rows of waves)
    const int wc64  = (w & 3) * 64;      // wave N-offset (4 cols of waves)
    const int w8    = w << 3;

    // staging: thread t -> physical 16B chunk (t&7) of slab-row (t>>3);
    // physical chunk p of row r holds LOGICAL chunk p ^ (r&7) (conflict swizzle)
    const int sr   = tid >> 3;                       // 0..63
    const int kswz = ((tid & 7) ^ (sr & 7)) << 3;    // pre-swizzled global k-off

    // T1: XCD-chunked bijective swizzle; y-fastest inside a chunk so the
    // ~32 co-resident blocks per XCD share one B-tile slice in that XCD's L2.
    const int orig = blockIdx.x;
    const int wgid = (orig & 7) * CPX + (orig >> 3);
    const int xb   = wgid >> 5;          // / NYT
    const int yb   = wgid & 31;

    const int rowA = yb * BM;
    const int colB = xb * BN;

    const u16* Ab = A  + (size_t)(rowA + sr) * N_IN + kswz;
    const u16* Bb = Bt + (size_t)(colB + sr) * N_IN + kswz;

    floatx4 acc[8][4];
    #pragma unroll
    for (int i = 0; i < 8; ++i)
        #pragma unroll
        for (int j = 0; j < 4; ++j)
            acc[i][j] = {0.f, 0.f, 0.f, 0.f};

    // prologue: tile0 A+B, tile1 A  (12 calls) -> vmcnt(4) leaves tile1-A in flight
    GLL_HALF(sA[0], Ab, 0, 0);   GLL_HALF(sA[0], Ab, 128, 0);
    GLL_HALF(sB[0], Bb, 0, 0);   GLL_HALF(sB[0], Bb, 128, 0);
    GLL_HALF(sA[1], Ab, 0, BK);  GLL_HALF(sA[1], Ab, 128, BK);
    VM4;
    __builtin_amdgcn_s_barrier();

    int kb = 0;
    #pragma clang loop unroll(disable)
    for (int i = 0; i < 31; ++i) {          // tiles 0..61
        TILE(0, kb, 1, 1, VM4);
        TILE(1, kb + BK, 1, 1, VM4);
        kb += 2 * BK;
    }
    TILE(0, kb, 1, 0, VM0);                 // tile 62: stage B63, drain all
    TILE(1, kb + BK, 0, 0, NOWAIT);         // tile 63: pure compute

    // epilogue: D col = lane&15, row = lquad*4 + reg  [m89-verified layout]
    // nontemporal: C is a 344 MB stream; keep it from evicting A/B out of L3.
    #pragma unroll
    for (int mi = 0; mi < 8; ++mi) {
        #pragma unroll
        for (int ni = 0; ni < 4; ++ni) {
            floatx4 v = acc[mi][ni];
            int gc  = colB + wc64 + ni * 16 + l16;
            int gr0 = rowA + wr128 + mi * 16 + lquad * 4;
            #pragma unroll
            for (int r = 0; r < 4; ++r)
                __builtin_nontemporal_store(v[r], &C[(size_t)(gr0 + r) * K_OUT + gc]);
        }
    }
}

extern "C" void kernel_launch(void* const* d_in, const int* in_sizes, int n_in,
                              void* d_out, int out_size, void* d_ws, size_t ws_size,
                              hipStream_t stream) {
    const float* x      = (const float*)d_in[0];
    const int*   Wq     = (const int*)  d_in[1];
    const float* zeros  = (const float*)d_in[2];
    const float* scales = (const float*)d_in[3];
    const float* mu1    = (const float*)d_in[4];
    const float* mu2    = (const float*)d_in[5];
    float* out = (float*)d_out;

    u16* xm = (u16*)d_ws;                                        // 67,108,864 B
    u16* Wb = (u16*)((char*)d_ws + (size_t)B_SZ * N_IN * 2);     // 90,177,536 B

    hipLaunchKernelGGL(prep_x_kernel, dim3((B_SZ * N_IN) / 2048), dim3(256), 0, stream,
                       x, mu1, xm);
    hipLaunchKernelGGL(prep_w_kernel, dim3((K_OUT * N_IN) / 2048), dim3(256), 0, stream,
                       Wq, zeros, scales, mu2, Wb);
    hipLaunchKernelGGL(gemm_bt_kernel, dim3(NWG), dim3(512), 0, stream,
                       xm, Wb, out);
}

// Round 3
// 1317.612 us; speedup vs baseline: 1.1181x; 1.1181x over previous
//
#include <hip/hip_runtime.h>
#include <hip/hip_bf16.h>
#include <stdint.h>

typedef unsigned short u16;

#define K_OUT 11008
#define N_IN  4096
#define B_SZ  8192
#define NGRP  64

#define BM 256
#define BN 256
#define BK 64

#define NXT (K_OUT / BN)   // 43 tiles along out-K
#define NYT (B_SZ / BM)    // 32 tiles along batch
#define NWG (NXT * NYT)    // 1376 (% 8 == 0 -> bijective XCD chunking)
#define CPX (NWG / 8)      // 172 blocks per XCD chunk

typedef __attribute__((ext_vector_type(8))) __bf16 bf16x8;
typedef __attribute__((ext_vector_type(8))) u16 u16x8;
typedef __attribute__((ext_vector_type(4))) float floatx4;

__device__ __forceinline__ u16 f2bf(float f) {
    union { float f; uint32_t u; } v; v.f = f;
    uint32_t u = v.u;
    return (u16)((u + 0x7fffu + ((u >> 16) & 1u)) >> 16);  // RNE
}

__device__ __forceinline__ void gll16(const u16* g, u16* l) {
    __builtin_amdgcn_global_load_lds(
        (const __attribute__((address_space(1))) unsigned int*)g,
        (__attribute__((address_space(3))) unsigned int*)l,
        16, 0, 0);
}

// xm[b,n] = bf16(x[b,n] * mu1[n]) ; 8 elems/thread, 16B stores
__global__ __launch_bounds__(256) void prep_x_kernel(const float* __restrict__ x,
                                                     const float* __restrict__ mu1,
                                                     u16* __restrict__ xm) {
    int i = (blockIdx.x * blockDim.x + threadIdx.x) * 8;
    float4 xv0 = *(const float4*)(x + i);
    float4 xv1 = *(const float4*)(x + i + 4);
    int n = i & (N_IN - 1);
    float4 mv0 = *(const float4*)(mu1 + n);
    float4 mv1 = *(const float4*)(mu1 + n + 4);
    u16x8 o;
    o[0] = f2bf(xv0.x * mv0.x); o[1] = f2bf(xv0.y * mv0.y);
    o[2] = f2bf(xv0.z * mv0.z); o[3] = f2bf(xv0.w * mv0.w);
    o[4] = f2bf(xv1.x * mv1.x); o[5] = f2bf(xv1.y * mv1.y);
    o[6] = f2bf(xv1.z * mv1.z); o[7] = f2bf(xv1.w * mv1.w);
    *(u16x8*)(xm + i) = o;
}

// Wb[k,n] = bf16((Wq[k,n] - zeros[k,g]) * scales[k,g] * mu2[k]) ; 8 elems/thread
__global__ __launch_bounds__(256) void prep_w_kernel(const int* __restrict__ Wq,
                                                     const float* __restrict__ zeros,
                                                     const float* __restrict__ scales,
                                                     const float* __restrict__ mu2,
                                                     u16* __restrict__ Wb) {
    int i = (blockIdx.x * blockDim.x + threadIdx.x) * 8;
    int k = i >> 12;            // / N_IN
    int n = i & (N_IN - 1);
    int g = n >> 6;             // all 8 elems same group (8 | 64)
    float z = zeros[k * NGRP + g];
    float s = scales[k * NGRP + g] * mu2[k];
    int4 q0 = *(const int4*)(Wq + i);
    int4 q1 = *(const int4*)(Wq + i + 4);
    u16x8 o;
    o[0] = f2bf(((float)q0.x - z) * s); o[1] = f2bf(((float)q0.y - z) * s);
    o[2] = f2bf(((float)q0.z - z) * s); o[3] = f2bf(((float)q0.w - z) * s);
    o[4] = f2bf(((float)q1.x - z) * s); o[5] = f2bf(((float)q1.y - z) * s);
    o[6] = f2bf(((float)q1.z - z) * s); o[7] = f2bf(((float)q1.w - z) * s);
    *(u16x8*)(Wb + i) = o;
}

// ---------------------------------------------------------------------------
// C[M=8192, K_OUT=11008] = A[M,4096] * Bt[K_OUT,4096]^T, bf16 in / fp32 out.
// 256x256 tile, BK=64, 8 waves (2Mx4N), each wave 128x64 via 8x4 x 16x16x32 mfma.
// 8-phase schedule, DEEP counted-vmcnt pipeline (>=4-phase issue-to-consume,
// m201-depth), setprio (T5), XOR-swizzled LDS (T2, 0 conflicts), XCD swizzle (T1).
//
// vmcnt ledger (instr/wave; 2 per half, 8 per tile):
//   liveness: sB[buf]'s data is register-resident after ph1 (all waves' ds_reads
//   complete before their ph1 lgkmcnt(0); ph1-end barrier publishes that), so
//   B(T+2) is staged INTO sB[buf] during tile T: h0 @ph2, h1 @ph3. A(T+2) into
//   sA[buf] @ph3 (sA[buf] reads end at ph2). Per tile: 8 issues, all in ph2/ph3.
//   tile-end wait = vmcnt(8) = exactly this tile's issues -> everything needed
//   at T+1 ph0 was issued >=4 phases earlier, at T+2 ph0 >=5 phases.
//   prologue: A0(4) B0(4) A1(4) B1(4) -> vmcnt(8): tile0 ready, tile1 in flight.
//   tail: tiles 62/63 stage nothing; 62 ends vmcnt(0) (drain B63/A63), 63 free.
// ---------------------------------------------------------------------------

#define GLL_HALF(Sdst, Gbase, R0, KB) do {                                        \
    gll16((Gbase) + (size_t)(R0) * N_IN + (KB), &(Sdst)[((R0) + w8) * BK]);       \
    gll16((Gbase) + (size_t)((R0) + 64) * N_IN + (KB), &(Sdst)[((R0) + 64 + w8) * BK]); \
} while (0)

#define VM8 asm volatile("s_waitcnt vmcnt(8)" ::: "memory")
#define VM0 asm volatile("s_waitcnt vmcnt(0)" ::: "memory")
#define NOWAIT ((void)0)

#define PHASE_MID()                                              \
    __builtin_amdgcn_sched_barrier(0);                           \
    __builtin_amdgcn_s_barrier();                                \
    asm volatile("s_waitcnt lgkmcnt(0)" ::: "memory");           \
    __builtin_amdgcn_sched_barrier(0);                           \
    __builtin_amdgcn_s_setprio(1);

#define PHASE_END()                                              \
    __builtin_amdgcn_s_setprio(0);                               \
    __builtin_amdgcn_sched_barrier(0);                           \
    __builtin_amdgcn_s_barrier();                                \
    __builtin_amdgcn_sched_barrier(0);

#define TILE(BUF, KB, DO_B, DO_A, WAITSTMT) do {                                  \
    const u16* sAb = sA[BUF];                                                     \
    const u16* sBb = sB[BUF];                                                     \
    bf16x8 aL[4][2], aH[4][2], bL[2][2], bH[2][2];                                \
    /* ---- phase 0: read A-lo(8) + B-lo(4); MFMA q0 ---- */                      \
    _Pragma("unroll")                                                             \
    for (int mi = 0; mi < 4; ++mi) {                                              \
        const int row = wr128 + mi * 16 + l16;                                    \
        _Pragma("unroll")                                                         \
        for (int ks = 0; ks < 2; ++ks) {                                          \
            const int pc = (ks * 4 + lquad) ^ (row & 7);                          \
            aL[mi][ks] = *(const bf16x8*)&sAb[row * BK + pc * 8];                 \
        }                                                                         \
    }                                                                             \
    _Pragma("unroll")                                                             \
    for (int ni = 0; ni < 2; ++ni) {                                              \
        const int row = wc64 + ni * 16 + l16;                                     \
        _Pragma("unroll")                                                         \
        for (int ks = 0; ks < 2; ++ks) {                                          \
            const int pc = (ks * 4 + lquad) ^ (row & 7);                          \
            bL[ni][ks] = *(const bf16x8*)&sBb[row * BK + pc * 8];                 \
        }                                                                         \
    }                                                                             \
    PHASE_MID()                                                                   \
    _Pragma("unroll")                                                             \
    for (int ks = 0; ks < 2; ++ks)                                                \
        _Pragma("unroll")                                                         \
        for (int mi = 0; mi < 4; ++mi)                                            \
            _Pragma("unroll")                                                     \
            for (int ni = 0; ni < 2; ++ni)                                        \
                acc[mi][ni] = __builtin_amdgcn_mfma_f32_16x16x32_bf16(            \
                    aL[mi][ks], bL[ni][ks], acc[mi][ni], 0, 0, 0);                \
    PHASE_END()                                                                   \
    /* ---- phase 1: read B-hi(4); MFMA q1.  after this, sB[BUF] is dead ---- */  \
    _Pragma("unroll")                                                             \
    for (int ni = 0; ni < 2; ++ni) {                                              \
        const int row = wc64 + (ni + 2) * 16 + l16;                               \
        _Pragma("unroll")                                                         \
        for (int ks = 0; ks < 2; ++ks) {                                          \
            const int pc = (ks * 4 + lquad) ^ (row & 7);                          \
            bH[ni][ks] = *(const bf16x8*)&sBb[row * BK + pc * 8];                 \
        }                                                                         \
    }                                                                             \
    PHASE_MID()                                                                   \
    _Pragma("unroll")                                                             \
    for (int ks = 0; ks < 2; ++ks)                                                \
        _Pragma("unroll")                                                         \
        for (int mi = 0; mi < 4; ++mi)                                            \
            _Pragma("unroll")                                                     \
            for (int ni = 0; ni < 2; ++ni)                                        \
                acc[mi][ni + 2] = __builtin_amdgcn_mfma_f32_16x16x32_bf16(        \
                    aL[mi][ks], bH[ni][ks], acc[mi][ni + 2], 0, 0, 0);            \
    PHASE_END()                                                                   \
    /* ---- phase 2: read A-hi(8); stage B(T+2)h0 into sB[BUF]; MFMA q2 ---- */   \
    _Pragma("unroll")                                                             \
    for (int mi = 0; mi < 4; ++mi) {                                              \
        const int row = wr128 + (mi + 4) * 16 + l16;                              \
        _Pragma("unroll")                                                         \
        for (int ks = 0; ks < 2; ++ks) {                                          \
            const int pc = (ks * 4 + lquad) ^ (row & 7);                          \
            aH[mi][ks] = *(const bf16x8*)&sAb[row * BK + pc * 8];                 \
        }                                                                         \
    }                                                                             \
    if (DO_B) GLL_HALF(sB[BUF], Bb, 0, (KB) + 2 * BK);                            \
    PHASE_MID()                                                                   \
    _Pragma("unroll")                                                             \
    for (int ks = 0; ks < 2; ++ks)                                                \
        _Pragma("unroll")                                                         \
        for (int mi = 0; mi < 4; ++mi)                                            \
            _Pragma("unroll")                                                     \
            for (int ni = 0; ni < 2; ++ni)                                        \
                acc[mi + 4][ni] = __builtin_amdgcn_mfma_f32_16x16x32_bf16(        \
                    aH[mi][ks], bL[ni][ks], acc[mi + 4][ni], 0, 0, 0);            \
    PHASE_END()                                                                   \
    /* ---- phase 3: stage B(T+2)h1 + A(T+2); MFMA q3; vmcnt(8) ---- */           \
    if (DO_B) GLL_HALF(sB[BUF], Bb, 128, (KB) + 2 * BK);                          \
    if (DO_A) {                                                                   \
        GLL_HALF(sA[BUF], Ab, 0, (KB) + 2 * BK);                                  \
        GLL_HALF(sA[BUF], Ab, 128, (KB) + 2 * BK);                                \
    }                                                                             \
    __builtin_amdgcn_sched_barrier(0);                                            \
    __builtin_amdgcn_s_barrier();                                                 \
    __builtin_amdgcn_s_setprio(1);                                                \
    _Pragma("unroll")                                                             \
    for (int ks = 0; ks < 2; ++ks)                                                \
        _Pragma("unroll")                                                         \
        for (int mi = 0; mi < 4; ++mi)                                            \
            _Pragma("unroll")                                                     \
            for (int ni = 0; ni < 2; ++ni)                                        \
                acc[mi + 4][ni + 2] = __builtin_amdgcn_mfma_f32_16x16x32_bf16(    \
                    aH[mi][ks], bH[ni][ks], acc[mi + 4][ni + 2], 0, 0, 0);        \
    __builtin_amdgcn_s_setprio(0);                                                \
    __builtin_amdgcn_sched_barrier(0);                                            \
    WAITSTMT;                                                                     \
    __builtin_amdgcn_s_barrier();                                                 \
    __builtin_amdgcn_sched_barrier(0);                                            \
} while (0)

__global__ __launch_bounds__(512, 2) void gemm_bt_kernel(const u16* __restrict__ A,
                                                         const u16* __restrict__ Bt,
                                                         float* __restrict__ C) {
    __shared__ __align__(16) u16 sA[2][BM * BK];   // 2 x 32 KB
    __shared__ __align__(16) u16 sB[2][BN * BK];   // 2 x 32 KB  (128 KiB total)

    const int tid   = threadIdx.x;
    const int w     = tid >> 6;          // wave 0..7
    const int lane  = tid & 63;
    const int lquad = lane >> 4;
    const int l16   = lane & 15;
    const int wr128 = (w >> 2) * 128;    // wave M-offset (2 rows of waves)
    const int wc64  = (w & 3) * 64;      // wave N-offset (4 cols of waves)
    const int w8    = w << 3;

    // staging: thread t -> physical 16B chunk (t&7) of slab-row (t>>3);
    // physical chunk p of row r holds LOGICAL chunk p ^ (r&7) (conflict swizzle)
    const int sr   = tid >> 3;                       // 0..63
    const int kswz = ((tid & 7) ^ (sr & 7)) << 3;    // pre-swizzled global k-off

    // T1: XCD-chunked bijective swizzle; y-fastest inside a chunk so the
    // ~32 co-resident blocks per XCD share one B-tile slice in that XCD's L2.
    const int orig = blockIdx.x;
    const int wgid = (orig & 7) * CPX + (orig >> 3);
    const int xb   = wgid >> 5;          // / NYT
    const int yb   = wgid & 31;

    const int rowA = yb * BM;
    const int colB = xb * BN;

    const u16* Ab = A  + (size_t)(rowA + sr) * N_IN + kswz;
    const u16* Bb = Bt + (size_t)(colB + sr) * N_IN + kswz;

    floatx4 acc[8][4];
    #pragma unroll
    for (int i = 0; i < 8; ++i)
        #pragma unroll
        for (int j = 0; j < 4; ++j)
            acc[i][j] = {0.f, 0.f, 0.f, 0.f};

    // prologue: A0 B0 (tile0), A1 B1 (tile1) = 16 calls -> vmcnt(8):
    // tile0 arrived, tile1's 8 still in flight (consumed after tile0's vmcnt(8)).
    GLL_HALF(sA[0], Ab, 0, 0);   GLL_HALF(sA[0], Ab, 128, 0);
    GLL_HALF(sB[0], Bb, 0, 0);   GLL_HALF(sB[0], Bb, 128, 0);
    GLL_HALF(sA[1], Ab, 0, BK);  GLL_HALF(sA[1], Ab, 128, BK);
    GLL_HALF(sB[1], Bb, 0, BK);  GLL_HALF(sB[1], Bb, 128, BK);
    VM8;
    __builtin_amdgcn_s_barrier();

    int kb = 0;
    #pragma clang loop unroll(disable)
    for (int i = 0; i < 31; ++i) {          // tiles 0..61 (stage T+2 each)
        TILE(0, kb, 1, 1, VM8);
        TILE(1, kb + BK, 1, 1, VM8);
        kb += 2 * BK;
    }
    TILE(0, kb, 0, 0, VM0);                 // tile 62: no stage, drain all
    TILE(1, kb + BK, 0, 0, NOWAIT);         // tile 63: pure compute

    // epilogue: D col = lane&15, row = lquad*4 + reg  [m89-verified layout]
    #pragma unroll
    for (int mi = 0; mi < 8; ++mi) {
        #pragma unroll
        for (int ni = 0; ni < 4; ++ni) {
            floatx4 v = acc[mi][ni];
            int gc  = colB + wc64 + ni * 16 + l16;
            int gr0 = rowA + wr128 + mi * 16 + lquad * 4;
            #pragma unroll
            for (int r = 0; r < 4; ++r)
                C[(size_t)(gr0 + r) * K_OUT + gc] = v[r];
        }
    }
}

extern "C" void kernel_launch(void* const* d_in, const int* in_sizes, int n_in,
                              void* d_out, int out_size, void* d_ws, size_t ws_size,
                              hipStream_t stream) {
    const float* x      = (const float*)d_in[0];
    const int*   Wq     = (const int*)  d_in[1];
    const float* zeros  = (const float*)d_in[2];
    const float* scales = (const float*)d_in[3];
    const float* mu1    = (const float*)d_in[4];
    const float* mu2    = (const float*)d_in[5];
    float* out = (float*)d_out;

    u16* xm = (u16*)d_ws;                                        // 67,108,864 B
    u16* Wb = (u16*)((char*)d_ws + (size_t)B_SZ * N_IN * 2);     // 90,177,536 B

    hipLaunchKernelGGL(prep_x_kernel, dim3((B_SZ * N_IN) / 2048), dim3(256), 0, stream,
                       x, mu1, xm);
    hipLaunchKernelGGL(prep_w_kernel, dim3((K_OUT * N_IN) / 2048), dim3(256), 0, stream,
                       Wq, zeros, scales, mu2, Wb);
    hipLaunchKernelGGL(gemm_bt_kernel, dim3(NWG), dim3(512), 0, stream,
                       xm, Wb, out);
}